// Round 18
// baseline (457.431 us; speedup 1.0000x reference)
//
#include <hip/hip_runtime.h>
#include <cstddef>

#define SCALE 0.17677669529663687f
#define EPS 1e-5f

typedef __attribute__((ext_vector_type(8))) __bf16 bf16x8;
typedef __attribute__((ext_vector_type(16))) float f32x16;
typedef __attribute__((ext_vector_type(8))) unsigned short ushort8;

__device__ __forceinline__ unsigned short f2bf(float f) {
    unsigned u = __float_as_uint(f);
    return (unsigned short)((u + 0x7fffu + ((u >> 16) & 1u)) >> 16);
}
__device__ __forceinline__ float bf2f(unsigned short h) {
    return __uint_as_float(((unsigned)h) << 16);
}
__device__ __forceinline__ unsigned cvt_pk_bf16(float a, float b) {
    unsigned r;
    asm("v_cvt_pk_bf16_f32 %0, %1, %2" : "=v"(r) : "v"(a), "v"(b));
    return r;
}

#define MFMA32(a, b, c) __builtin_amdgcn_mfma_f32_32x32x16_bf16(a, b, c, 0, 0, 0)

#define GLD_LDS16(gsrc, ldst) \
    __builtin_amdgcn_global_load_lds((const __attribute__((address_space(1))) void*)(gsrc), \
                                     (__attribute__((address_space(3))) void*)(ldst), 16, 0, 0)

// ============ prep: W -> 32x32x16 MFMA fragments, split hi/lo bf16 ===========
// K-order (cg-major): step s = cg*9+f; f=0 silu, f=1..8 rbf center f-1.
// fragIdx = ((s*MTT + mt)*2 + kf)*2 + hl. Frag 1024B lane-linear:
// lane l holds W row m = mt*32 + (l&31), k-slot j -> ch c = cg*32 + kf*16 + (l>>5)*8 + j.
__global__ __launch_bounds__(256)
void prep_frag32(const float* __restrict__ wb, const float* __restrict__ ws,
                 unsigned short* __restrict__ Wf, int MTT)
{
    int idx = blockIdx.x * 256 + threadIdx.x;
    int total = 27 * MTT * 4 * 64;
    if (idx >= total) return;
    int lane = idx & 63;
    int t = idx >> 6;
    int hl = t & 1, kf = (t >> 1) & 1;
    int mt = (t >> 2) % MTT, s = (t >> 2) / MTT;
    int cg = s / 9, f = s - cg * 9;
    int m = mt * 32 + (lane & 31);
    int kg = lane >> 5;
    ushort8 v;
    #pragma unroll
    for (int j = 0; j < 8; ++j) {
        int c = cg * 32 + kf * 16 + kg * 8 + j;
        float w = (f == 0) ? wb[m * 96 + c] : ws[(m * 96 + c) * 8 + (f - 1)];
        unsigned short hi = f2bf(w);
        v[j] = hl ? f2bf(w - bf2f(hi)) : hi;
    }
    *reinterpret_cast<ushort8*>(Wf + (size_t)t * 512 + lane * 8) = v;
}

// ============ kernel A: phi = A operand, W = B in LDS (R16 verified) =========
// Block: 96 rows (mb) x 256 cols. 4 waves; wave = 64 cols (2 tiles) x 3 mt.
// LDS dbuf 24 KiB; 2 blocks/CU (208 unified regs; structural, R11/R12/R16).
// R17 lesson: qbuf+14-barriers regressed (+14us, FETCH +23MB) -> dbuf kept.
// MODE 0: windowed gather (L1), out window-major qkv[w*4896 + l*288 + m]
// MODE 2: lin64 gather   (L2), out col-major qk[p*192 + m]
template<int MTT, int MODE>
__global__ __launch_bounds__(256, 2)
void kan_mfma(const float* __restrict__ xin, const float* __restrict__ token,
              const unsigned short* __restrict__ Wf, float* __restrict__ out)
{
    __shared__ __align__(16) char smem[2 * 12 * 1024];

    const int tid = threadIdx.x, lane = tid & 63, wid = tid >> 6;
    const int kg = lane >> 5, cl = lane & 31;

    int n0, mb;
    if (MODE == 0) {
        int xcd = blockIdx.x & 7, idx = blockIdx.x >> 3;   // 204 per XCD
        int nloc = idx / 3; mb = idx - nloc * 3;
        n0 = (xcd * 68 + nloc) * 256;
    } else {
        mb = blockIdx.x & 1; n0 = (blockIdx.x >> 1) * 256;
    }

    auto issueA = [&](int s, int buf) {
        #pragma unroll
        for (int c0 = 0; c0 < 3; ++c0) {
            int c = wid + c0 * 4;
            const unsigned short* src = Wf + ((size_t)s * MTT * 4 + mb * 12 + c) * 512 + lane * 8;
            GLD_LDS16(src, smem + (buf * 12 + c) * 1024);
        }
    };
    issueA(0, 0);

    // ---- per-thread: two columns (A rows) ----------------------------------
    const float* gbv[2];
    int gsv[2];
    #pragma unroll
    for (int nt = 0; nt < 2; ++nt) {
        int p = n0 + wid * 64 + nt * 32 + cl;
        if (MODE == 0) {
            int w = p / 17, l = p - w * 17;
            if (l == 0) { gbv[nt] = token; gsv[nt] = 1; }
            else {
                int b = w >> 6, wl = w & 63;
                int wx = wl >> 3, wy = wl & 7;
                int jj = l - 1, gx = jj >> 2, gy = jj & 3;
                gbv[nt] = xin + (size_t)b * 98304 + (wx * 4 + gx) * 32 + wy * 4 + gy;
                gsv[nt] = 1024;
            }
        } else {
            gbv[nt] = xin + (size_t)(p >> 6) * 6144 + (p & 63);
            gsv[nt] = 64;
        }
    }

    f32x16 acc[2][3];
    #pragma unroll
    for (int nt = 0; nt < 2; ++nt)
        #pragma unroll
        for (int mt = 0; mt < 3; ++mt)
            #pragma unroll
            for (int r = 0; r < 16; ++r) acc[nt][mt][r] = 0.f;

    float rr[2][16], du[2][16];
    bf16x8 pk[2][2];

    auto phiInit = [&](int cg) {
        #pragma unroll
        for (int nt = 0; nt < 2; ++nt) {
            float ph[16];
            #pragma unroll
            for (int t = 0; t < 2; ++t)
                #pragma unroll
                for (int j = 0; j < 8; ++j) {
                    int q = t * 8 + j;
                    float xv = gbv[nt][(size_t)(cg * 32 + t * 16 + kg * 8 + j) * gsv[nt]];
                    ph[q] = __fdividef(xv, 1.f + __expf(-xv));
                    float a = fmaf(xv, 1.75f, 3.5f);
                    rr[nt][q] = __expf(-a * a);
                    du[nt][q] = __expf(fminf(fmaf(a, 2.f, -1.f), 80.f));
                }
            #pragma unroll
            for (int t = 0; t < 2; ++t) {
                uint4 w;
                w.x = cvt_pk_bf16(ph[t * 8 + 0], ph[t * 8 + 1]);
                w.y = cvt_pk_bf16(ph[t * 8 + 2], ph[t * 8 + 3]);
                w.z = cvt_pk_bf16(ph[t * 8 + 4], ph[t * 8 + 5]);
                w.w = cvt_pk_bf16(ph[t * 8 + 6], ph[t * 8 + 7]);
                pk[nt][t] = *reinterpret_cast<bf16x8*>(&w);
            }
        }
    };
    auto phiRbf = [&](bool upd) {
        #pragma unroll
        for (int nt = 0; nt < 2; ++nt) {
            if (upd) {
                #pragma unroll
                for (int q = 0; q < 16; ++q) { rr[nt][q] *= du[nt][q]; du[nt][q] *= 0.1353352832366127f; }
            }
            #pragma unroll
            for (int t = 0; t < 2; ++t) {
                uint4 w;
                w.x = cvt_pk_bf16(rr[nt][t * 8 + 0], rr[nt][t * 8 + 1]);
                w.y = cvt_pk_bf16(rr[nt][t * 8 + 2], rr[nt][t * 8 + 3]);
                w.z = cvt_pk_bf16(rr[nt][t * 8 + 4], rr[nt][t * 8 + 5]);
                w.w = cvt_pk_bf16(rr[nt][t * 8 + 6], rr[nt][t * 8 + 7]);
                pk[nt][t] = *reinterpret_cast<bf16x8*>(&w);
            }
        }
    };

    #pragma unroll
    for (int s = 0; s < 27; ++s) {
        __syncthreads();
        if (s + 1 < 27) issueA(s + 1, (s + 1) & 1);
        const int fn = s % 9;
        if (fn == 0) phiInit(s / 9);
        else phiRbf(fn != 1);

        const char* Ab = smem + (s & 1) * 12288;
        #pragma unroll
        for (int mt = 0; mt < 3; ++mt) {
            const char* fb = Ab + mt * 4096 + lane * 16;
            bf16x8 b0h = *reinterpret_cast<const bf16x8*>(fb);
            bf16x8 b0l = *reinterpret_cast<const bf16x8*>(fb + 1024);
            bf16x8 b1h = *reinterpret_cast<const bf16x8*>(fb + 2048);
            bf16x8 b1l = *reinterpret_cast<const bf16x8*>(fb + 3072);
            #pragma unroll
            for (int nt = 0; nt < 2; ++nt) {
                acc[nt][mt] = MFMA32(pk[nt][0], b0h, acc[nt][mt]);
                acc[nt][mt] = MFMA32(pk[nt][0], b0l, acc[nt][mt]);
                acc[nt][mt] = MFMA32(pk[nt][1], b1h, acc[nt][mt]);
                acc[nt][mt] = MFMA32(pk[nt][1], b1l, acc[nt][mt]);
            }
        }
    }

    // ---- epilogue: D[p][m]; lane holds m = mt*32 + cl, p = base + (r&3)+8*(r>>2)+4*kg
    if (MODE == 0) {
        #pragma unroll
        for (int nt = 0; nt < 2; ++nt)
            #pragma unroll
            for (int r = 0; r < 16; ++r) {
                int p = n0 + wid * 64 + nt * 32 + (r & 3) + 8 * (r >> 2) + 4 * kg;
                int w = p / 17, l = p - w * 17;
                float* dst = out + (size_t)w * 4896 + l * 288 + mb * 96 + cl;
                dst[0]  = acc[nt][0][r];
                dst[32] = acc[nt][1][r];
                dst[64] = acc[nt][2][r];
            }
    } else {
        #pragma unroll
        for (int nt = 0; nt < 2; ++nt)
            #pragma unroll
            for (int r = 0; r < 16; ++r) {
                int p = n0 + wid * 64 + nt * 32 + (r & 3) + 8 * (r >> 2) + 4 * kg;
                float* dst = out + (size_t)p * 192 + mb * 96 + cl;
                dst[0]  = acc[nt][0][r];
                dst[32] = acc[nt][1][r];
                dst[64] = acc[nt][2][r];
            }
    }
}

// ============ kernel B: W = A-operand from LDS, phi staged in LDS (R9) =======
// L3 only: 96 rows x 128 cols, 4 waves, wave = 32-col tile x 3 mt.
// LDS: A dbuf 24 KiB + phi dbuf 16 KiB. Direct out[b][96][1024] stores.
__global__ __launch_bounds__(256, 4)
void kan_mfma_fmap(const float* __restrict__ xin,
                   const unsigned short* __restrict__ Wf, float* __restrict__ out)
{
    __shared__ __align__(16) char smem[40960];
    char* sA = smem;             // 2*12 KiB
    char* sB = smem + 24576;     // 2*8 KiB

    const int tid = threadIdx.x, lane = tid & 63, wid = tid >> 6;

    int xcd = blockIdx.x & 7;
    int n0 = (xcd * 128 + (blockIdx.x >> 3)) * 128;

    auto issueA = [&](int s, int buf) {
        #pragma unroll
        for (int c0 = 0; c0 < 3; ++c0) {
            int c = wid + c0 * 4;
            const unsigned short* src = Wf + ((size_t)s * 12 + c) * 512 + lane * 8;
            GLD_LDS16(src, sA + (buf * 12 + c) * 1024);
        }
    };
    issueA(0, 0);

    const int ct = tid & 127, kgp = tid >> 7;
    const int lane_in = kgp * 32 + (ct & 31);
    const int p = n0 + ct;
    const float* gbase = xin + (size_t)(p >> 10) * 98304 + (p & 1023);

    f32x16 acc[3];
    #pragma unroll
    for (int mt = 0; mt < 3; ++mt)
        #pragma unroll
        for (int r = 0; r < 16; ++r) acc[mt][r] = 0.f;

    float rr[16], du[16];

    auto phiInit = [&](int cg, char* d0, char* d1) {
        float ph[16];
        #pragma unroll
        for (int t = 0; t < 2; ++t)
            #pragma unroll
            for (int j = 0; j < 8; ++j) {
                int q = t * 8 + j;
                float xv = gbase[(size_t)(cg * 32 + t * 16 + kgp * 8 + j) * 1024];
                ph[q] = __fdividef(xv, 1.f + __expf(-xv));
                float a = fmaf(xv, 1.75f, 3.5f);
                rr[q] = __expf(-a * a);
                du[q] = __expf(fminf(fmaf(a, 2.f, -1.f), 80.f));
            }
        uint4 w0, w1;
        w0.x = cvt_pk_bf16(ph[0], ph[1]);  w0.y = cvt_pk_bf16(ph[2], ph[3]);
        w0.z = cvt_pk_bf16(ph[4], ph[5]);  w0.w = cvt_pk_bf16(ph[6], ph[7]);
        w1.x = cvt_pk_bf16(ph[8], ph[9]);  w1.y = cvt_pk_bf16(ph[10], ph[11]);
        w1.z = cvt_pk_bf16(ph[12], ph[13]); w1.w = cvt_pk_bf16(ph[14], ph[15]);
        *reinterpret_cast<uint4*>(d0) = w0;
        *reinterpret_cast<uint4*>(d1) = w1;
    };
    auto phiRbf = [&](bool upd, char* d0, char* d1) {
        if (upd) {
            #pragma unroll
            for (int q = 0; q < 16; ++q) { rr[q] *= du[q]; du[q] *= 0.1353352832366127f; }
        }
        uint4 w0, w1;
        w0.x = cvt_pk_bf16(rr[0], rr[1]);  w0.y = cvt_pk_bf16(rr[2], rr[3]);
        w0.z = cvt_pk_bf16(rr[4], rr[5]);  w0.w = cvt_pk_bf16(rr[6], rr[7]);
        w1.x = cvt_pk_bf16(rr[8], rr[9]);  w1.y = cvt_pk_bf16(rr[10], rr[11]);
        w1.z = cvt_pk_bf16(rr[12], rr[13]); w1.w = cvt_pk_bf16(rr[14], rr[15]);
        *reinterpret_cast<uint4*>(d0) = w0;
        *reinterpret_cast<uint4*>(d1) = w1;
    };

    phiInit(0, sB + (ct >> 5) * 1024 + lane_in * 16,
               sB + (4 + (ct >> 5)) * 1024 + lane_in * 16);

    #pragma unroll
    for (int s = 0; s < 27; ++s) {
        int sb = s & 1;
        __syncthreads();
        if (s + 1 < 27) issueA(s + 1, (s + 1) & 1);
        {
            const char* Ab = sA + sb * 12288;
            const char* Bb = sB + sb * 8192;
            bf16x8 b0 = *reinterpret_cast<const bf16x8*>(Bb + wid * 1024 + lane * 16);
            bf16x8 b1 = *reinterpret_cast<const bf16x8*>(Bb + (4 + wid) * 1024 + lane * 16);
            #pragma unroll
            for (int mt = 0; mt < 3; ++mt) {
                const char* fb = Ab + mt * 4096 + lane * 16;
                bf16x8 a0 = *reinterpret_cast<const bf16x8*>(fb);
                bf16x8 a1 = *reinterpret_cast<const bf16x8*>(fb + 1024);
                bf16x8 a2 = *reinterpret_cast<const bf16x8*>(fb + 2048);
                bf16x8 a3 = *reinterpret_cast<const bf16x8*>(fb + 3072);
                acc[mt] = MFMA32(a0, b0, acc[mt]);
                acc[mt] = MFMA32(a1, b0, acc[mt]);
                acc[mt] = MFMA32(a2, b1, acc[mt]);
                acc[mt] = MFMA32(a3, b1, acc[mt]);
            }
        }
        if (s + 1 < 27) {
            char* d0 = sB + ((s + 1) & 1) * 8192 + (ct >> 5) * 1024 + lane_in * 16;
            int fn = (s + 1) % 9;
            if (fn == 0) phiInit((s + 1) / 9, d0, d0 + 4096);
            else phiRbf(fn != 1, d0, d0 + 4096);
        }
    }

    // C/D 32x32: col = lane&31, row = (r&3)+8*(r>>2)+4*(lane>>5)
    const int colL = n0 + wid * 32 + (lane & 31);
    #pragma unroll
    for (int mt = 0; mt < 3; ++mt) {
        #pragma unroll
        for (int r = 0; r < 16; ++r) {
            int row = mt * 32 + (r & 3) + 8 * (r >> 2) + 4 * (lane >> 5);
            out[(size_t)(colL >> 10) * 98304 + (size_t)row * 1024 + (colL & 1023)] = acc[mt][r];
        }
    }
}

// ============ window feature-attention + fused LN/GELU =======================
// qkv window-major; gt rows are block-local -> LN+GELU in-block, write hh.
__global__ __launch_bounds__(256)
void attn1(const float* __restrict__ qkv, const float* __restrict__ lng,
           const float* __restrict__ lnb, float* __restrict__ gf,
           float* __restrict__ hh)
{
    __shared__ float sw[17][288];
    __shared__ float sa[3][32][33];
    __shared__ float sgt[3][32];
    const int w = blockIdx.x, tid = threadIdx.x;

    const float4* src = reinterpret_cast<const float4*>(qkv + (size_t)w * 4896);
    float4* dstl = reinterpret_cast<float4*>(&sw[0][0]);
    for (int e = tid; e < 1224; e += 256) dstl[e] = src[e];
    __syncthreads();

    for (int e = tid; e < 3072; e += 256) {
        int h = e >> 10, r = e & 1023, i = r >> 5, j = r & 31;
        float s = 0.f;
        #pragma unroll
        for (int l = 0; l < 17; ++l) s += sw[l][h * 32 + i] * sw[l][96 + h * 32 + j];
        sa[h][i][j] = s * SCALE;
    }
    __syncthreads();
    if (tid < 96) {
        int h = tid >> 5, i = tid & 31;
        float m = -1e30f;
        for (int j = 0; j < 32; ++j) m = fmaxf(m, sa[h][i][j]);
        float sum = 0.f;
        for (int j = 0; j < 32; ++j) { float e_ = __expf(sa[h][i][j] - m); sa[h][i][j] = e_; sum += e_; }
        float inv = 1.f / sum;
        for (int j = 0; j < 32; ++j) sa[h][i][j] *= inv;
    }
    __syncthreads();
    const int b = w >> 6, wl = w & 63;
    for (int e = tid; e < 1632; e += 256) {
        int h = e / 544, r = e - h * 544, l = r >> 5, i = r & 31;
        float s = 0.f;
        #pragma unroll
        for (int j = 0; j < 32; ++j) s += sa[h][i][j] * sw[l][192 + h * 32 + j];
        if (l == 0) sgt[h][i] = s;
        else        gf[((((size_t)b * 3 + h) * 64 + wl) * 16 + (l - 1)) * 32 + i] = s;
    }
    __syncthreads();
    if (tid < 96) {
        int h = tid >> 5, d = tid & 31;
        float xv = sgt[h][d];
        float s1 = xv, s2 = xv * xv;
        #pragma unroll
        for (int m = 16; m >= 1; m >>= 1) { s1 += __shfl_xor(s1, m, 32); s2 += __shfl_xor(s2, m, 32); }
        float mu = s1 * (1.f / 32.f);
        float var = s2 * (1.f / 32.f) - mu * mu;
        float hv = (xv - mu) * rsqrtf(var + EPS) * lng[d] + lnb[d];
        float g = 0.5f * hv * (1.f + erff(hv * 0.70710678118654752f));
        hh[((size_t)b * 96 + h * 32 + d) * 64 + wl] = g;
    }
}

// ---------------- window-token attention: dots + softmax (qk col-major) ------
__global__ __launch_bounds__(256)
void attn2a(const float* __restrict__ qk, float* __restrict__ wattn)
{
    int bh = blockIdx.x;
    int b = bh / 3, h = bh - b * 3;
    __shared__ float swq[64][33];
    __shared__ float swk[64][33];
    __shared__ float sd[64][65];
    int tid = threadIdx.x;
    for (int e = tid; e < 2048; e += 256) {
        int i = e >> 5, d = e & 31;
        const float* row = qk + ((size_t)b * 64 + i) * 192 + h * 64;
        swq[i][d] = row[d] * SCALE;
        swk[i][d] = row[32 + d];
    }
    __syncthreads();
    for (int e = tid; e < 4096; e += 256) {
        int i = e >> 6, j = e & 63;
        float s = 0.f;
        #pragma unroll
        for (int d = 0; d < 32; ++d) s += swq[i][d] * swk[j][d];
        sd[i][j] = s;
    }
    __syncthreads();
    if (tid < 64) {
        float m = -1e30f;
        for (int j = 0; j < 64; ++j) m = fmaxf(m, sd[tid][j]);
        float sum = 0.f;
        for (int j = 0; j < 64; ++j) { float e_ = __expf(sd[tid][j] - m); sd[tid][j] = e_; sum += e_; }
        float inv = 1.f / sum;
        for (int j = 0; j < 64; ++j) sd[tid][j] *= inv;
    }
    __syncthreads();
    for (int e = tid; e < 4096; e += 256)
        wattn[(size_t)bh * 4096 + e] = sd[e >> 6][e & 63];
}

// ---------------- agg = attn @ gf, scatter to fmap (b,96,32,32) --------------
__global__ __launch_bounds__(256)
void attn2b(const float* __restrict__ wattn, const float* __restrict__ gf,
            float* __restrict__ fmap)
{
    int blk = blockIdx.x;
    int ct = blk & 3, bh = blk >> 2;
    int b = bh / 3, h = bh - b * 3;
    __shared__ float sa[64][65];
    __shared__ float sg[64][129];
    int tid = threadIdx.x;
    for (int e = tid; e < 4096; e += 256) sa[e >> 6][e & 63] = wattn[(size_t)bh * 4096 + e];
    for (int e = tid; e < 8192; e += 256) {
        int j = e >> 7, c = e & 127;
        sg[j][c] = gf[((size_t)bh * 64 + j) * 512 + ct * 128 + c];
    }
    __syncthreads();
    int txc = tid & 31, tyi = tid >> 5;
    float acc[8][4];
    #pragma unroll
    for (int ii = 0; ii < 8; ++ii)
        #pragma unroll
        for (int c = 0; c < 4; ++c) acc[ii][c] = 0.f;
    for (int j = 0; j < 64; ++j) {
        float g0[4];
        #pragma unroll
        for (int c = 0; c < 4; ++c) g0[c] = sg[j][txc + c * 32];
        #pragma unroll
        for (int ii = 0; ii < 8; ++ii) {
            float a = sa[tyi + ii * 8][j];
            #pragma unroll
            for (int c = 0; c < 4; ++c) acc[ii][c] += a * g0[c];
        }
    }
    __syncthreads();
    #pragma unroll
    for (int ii = 0; ii < 8; ++ii)
        #pragma unroll
        for (int c = 0; c < 4; ++c)
            sg[tyi + ii * 8][txc + c * 32] = acc[ii][c];
    __syncthreads();
    for (int e = tid; e < 8192; e += 256) {
        int d = e >> 8;
        int nx = (e >> 5) & 7;
        int cp = e & 31;
        int ny = cp >> 2, gy = cp & 3;
        float v = sg[nx * 8 + ny][gy * 32 + d];
        fmap[(((size_t)b * 96 + h * 32 + d) * 32 + nx * 4 + ct) * 32 + cp] = v;
    }
}

// -----------------------------------------------------------------------------
extern "C" void kernel_launch(void* const* d_in, const int* in_sizes, int n_in,
                              void* d_out, int out_size, void* d_ws, size_t ws_size,
                              hipStream_t stream)
{
    const float* x      = (const float*)d_in[0];
    const float* tok    = (const float*)d_in[1];
    const float* qkv_wb = (const float*)d_in[2];
    const float* qkv_ws = (const float*)d_in[3];
    const float* lng    = (const float*)d_in[4];
    const float* lnb    = (const float*)d_in[5];
    const float* gt_wb  = (const float*)d_in[6];
    const float* gt_ws  = (const float*)d_in[7];
    const float* out_wb = (const float*)d_in[8];
    const float* out_ws = (const float*)d_in[9];
    float* out = (float*)d_out;
    float* ws  = (float*)d_ws;

    const size_t OFF_QKV   = 0;            // 40,108,032 floats (window-major)
    const size_t OFF_FMAP  = 0;            // reuses dead qkv region
    const size_t OFF_WATTN = 12582912;
    const size_t OFF_WF2   = 40108032;     // 165,888 floats
    const size_t OFF_GT    = OFF_WF2 + 165888;   // (unused; kept for layout)
    const size_t OFF_GF    = OFF_GT + 786432;
    const size_t OFF_HH    = OFF_GF + 12582912;
    const size_t OFF_QK    = OFF_HH + 786432;   // col-major [8192][192]
    const size_t OFF_WF1   = OFF_QK + 1572864;  // 248,832 floats
    const size_t OFF_WF3   = OFF_WF1 + 248832;  // 82,944 floats
    const size_t TOTAL     = OFF_WF3 + 82944;   // 56,334,336 floats
    if (ws_size < TOTAL * sizeof(float)) return;

    unsigned short* wf1 = (unsigned short*)(ws + OFF_WF1);
    unsigned short* wf2 = (unsigned short*)(ws + OFF_WF2);
    unsigned short* wf3 = (unsigned short*)(ws + OFF_WF3);

    prep_frag32<<<243, 256, 0, stream>>>(qkv_wb, qkv_ws, wf1, 9);
    prep_frag32<<<162, 256, 0, stream>>>(gt_wb,  gt_ws,  wf2, 6);
    prep_frag32<<< 81, 256, 0, stream>>>(out_wb, out_ws, wf3, 3);

    kan_mfma<9, 0><<<1632, 256, 0, stream>>>(x, tok, wf1, ws + OFF_QKV);
    attn1<<<8192, 256, 0, stream>>>(ws + OFF_QKV, lng, lnb, ws + OFF_GF, ws + OFF_HH);
    kan_mfma<6, 2><<<64, 256, 0, stream>>>(ws + OFF_HH, nullptr, wf2, ws + OFF_QK);
    attn2a<<<384, 256, 0, stream>>>(ws + OFF_QK, ws + OFF_WATTN);
    attn2b<<<1536, 256, 0, stream>>>(ws + OFF_WATTN, ws + OFF_GF, ws + OFF_FMAP);
    kan_mfma_fmap<<<1024, 256, 0, stream>>>(ws + OFF_FMAP, wf3, out);
}

// Round 19
// 456.144 us; speedup vs baseline: 1.0028x; 1.0028x over previous
//
#include <hip/hip_runtime.h>
#include <cstddef>

#define SCALE 0.17677669529663687f
#define EPS 1e-5f

typedef __attribute__((ext_vector_type(8))) __bf16 bf16x8;
typedef __attribute__((ext_vector_type(16))) float f32x16;
typedef __attribute__((ext_vector_type(8))) unsigned short ushort8;

__device__ __forceinline__ unsigned short f2bf(float f) {
    unsigned u = __float_as_uint(f);
    return (unsigned short)((u + 0x7fffu + ((u >> 16) & 1u)) >> 16);
}
__device__ __forceinline__ float bf2f(unsigned short h) {
    return __uint_as_float(((unsigned)h) << 16);
}
__device__ __forceinline__ unsigned cvt_pk_bf16(float a, float b) {
    unsigned r;
    asm("v_cvt_pk_bf16_f32 %0, %1, %2" : "=v"(r) : "v"(a), "v"(b));
    return r;
}

#define MFMA32(a, b, c) __builtin_amdgcn_mfma_f32_32x32x16_bf16(a, b, c, 0, 0, 0)

#define GLD_LDS16(gsrc, ldst) \
    __builtin_amdgcn_global_load_lds((const __attribute__((address_space(1))) void*)(gsrc), \
                                     (__attribute__((address_space(3))) void*)(ldst), 16, 0, 0)

// ============ prep: W -> 32x32x16 MFMA fragments, split hi/lo bf16 ===========
// K-order (cg-major): step s = cg*9+f; f=0 silu, f=1..8 rbf center f-1.
// fragIdx = ((s*MTT + mt)*2 + kf)*2 + hl. Frag 1024B lane-linear:
// lane l holds W row m = mt*32 + (l&31), k-slot j -> ch c = cg*32 + kf*16 + (l>>5)*8 + j.
__global__ __launch_bounds__(256)
void prep_frag32(const float* __restrict__ wb, const float* __restrict__ ws,
                 unsigned short* __restrict__ Wf, int MTT)
{
    int idx = blockIdx.x * 256 + threadIdx.x;
    int total = 27 * MTT * 4 * 64;
    if (idx >= total) return;
    int lane = idx & 63;
    int t = idx >> 6;
    int hl = t & 1, kf = (t >> 1) & 1;
    int mt = (t >> 2) % MTT, s = (t >> 2) / MTT;
    int cg = s / 9, f = s - cg * 9;
    int m = mt * 32 + (lane & 31);
    int kg = lane >> 5;
    ushort8 v;
    #pragma unroll
    for (int j = 0; j < 8; ++j) {
        int c = cg * 32 + kf * 16 + kg * 8 + j;
        float w = (f == 0) ? wb[m * 96 + c] : ws[(m * 96 + c) * 8 + (f - 1)];
        unsigned short hi = f2bf(w);
        v[j] = hl ? f2bf(w - bf2f(hi)) : hi;
    }
    *reinterpret_cast<ushort8*>(Wf + (size_t)t * 512 + lane * 8) = v;
}

// ============ kernel A: phi = A operand, W = B in LDS (R16 verified) =========
// Block: 96 rows (mb) x 256 cols. 4 waves; wave = 64 cols (2 tiles) x 3 mt.
// LDS dbuf 24 KiB; 2 blocks/CU (208 unified regs; structural, R11/R12/R16).
// R17 lesson: qbuf+14-barriers regressed (+14us, FETCH +23MB) -> dbuf kept.
// MODE 0: windowed gather (L1), out window-major qkv[w*4896 + l*288 + m]
// MODE 2: lin64 gather   (L2), out col-major qk[p*192 + m]
template<int MTT, int MODE>
__global__ __launch_bounds__(256, 2)
void kan_mfma(const float* __restrict__ xin, const float* __restrict__ token,
              const unsigned short* __restrict__ Wf, float* __restrict__ out)
{
    __shared__ __align__(16) char smem[2 * 12 * 1024];

    const int tid = threadIdx.x, lane = tid & 63, wid = tid >> 6;
    const int kg = lane >> 5, cl = lane & 31;

    int n0, mb;
    if (MODE == 0) {
        int xcd = blockIdx.x & 7, idx = blockIdx.x >> 3;   // 204 per XCD
        int nloc = idx / 3; mb = idx - nloc * 3;
        n0 = (xcd * 68 + nloc) * 256;
    } else {
        mb = blockIdx.x & 1; n0 = (blockIdx.x >> 1) * 256;
    }

    auto issueA = [&](int s, int buf) {
        #pragma unroll
        for (int c0 = 0; c0 < 3; ++c0) {
            int c = wid + c0 * 4;
            const unsigned short* src = Wf + ((size_t)s * MTT * 4 + mb * 12 + c) * 512 + lane * 8;
            GLD_LDS16(src, smem + (buf * 12 + c) * 1024);
        }
    };
    issueA(0, 0);

    // ---- per-thread: two columns (A rows) ----------------------------------
    const float* gbv[2];
    int gsv[2];
    #pragma unroll
    for (int nt = 0; nt < 2; ++nt) {
        int p = n0 + wid * 64 + nt * 32 + cl;
        if (MODE == 0) {
            int w = p / 17, l = p - w * 17;
            if (l == 0) { gbv[nt] = token; gsv[nt] = 1; }
            else {
                int b = w >> 6, wl = w & 63;
                int wx = wl >> 3, wy = wl & 7;
                int jj = l - 1, gx = jj >> 2, gy = jj & 3;
                gbv[nt] = xin + (size_t)b * 98304 + (wx * 4 + gx) * 32 + wy * 4 + gy;
                gsv[nt] = 1024;
            }
        } else {
            gbv[nt] = xin + (size_t)(p >> 6) * 6144 + (p & 63);
            gsv[nt] = 64;
        }
    }

    f32x16 acc[2][3];
    #pragma unroll
    for (int nt = 0; nt < 2; ++nt)
        #pragma unroll
        for (int mt = 0; mt < 3; ++mt)
            #pragma unroll
            for (int r = 0; r < 16; ++r) acc[nt][mt][r] = 0.f;

    float rr[2][16], du[2][16];
    bf16x8 pk[2][2];

    auto phiInit = [&](int cg) {
        #pragma unroll
        for (int nt = 0; nt < 2; ++nt) {
            float ph[16];
            #pragma unroll
            for (int t = 0; t < 2; ++t)
                #pragma unroll
                for (int j = 0; j < 8; ++j) {
                    int q = t * 8 + j;
                    float xv = gbv[nt][(size_t)(cg * 32 + t * 16 + kg * 8 + j) * gsv[nt]];
                    ph[q] = __fdividef(xv, 1.f + __expf(-xv));
                    float a = fmaf(xv, 1.75f, 3.5f);
                    rr[nt][q] = __expf(-a * a);
                    du[nt][q] = __expf(fminf(fmaf(a, 2.f, -1.f), 80.f));
                }
            #pragma unroll
            for (int t = 0; t < 2; ++t) {
                uint4 w;
                w.x = cvt_pk_bf16(ph[t * 8 + 0], ph[t * 8 + 1]);
                w.y = cvt_pk_bf16(ph[t * 8 + 2], ph[t * 8 + 3]);
                w.z = cvt_pk_bf16(ph[t * 8 + 4], ph[t * 8 + 5]);
                w.w = cvt_pk_bf16(ph[t * 8 + 6], ph[t * 8 + 7]);
                pk[nt][t] = *reinterpret_cast<bf16x8*>(&w);
            }
        }
    };
    auto phiRbf = [&](bool upd) {
        #pragma unroll
        for (int nt = 0; nt < 2; ++nt) {
            if (upd) {
                #pragma unroll
                for (int q = 0; q < 16; ++q) { rr[nt][q] *= du[nt][q]; du[nt][q] *= 0.1353352832366127f; }
            }
            #pragma unroll
            for (int t = 0; t < 2; ++t) {
                uint4 w;
                w.x = cvt_pk_bf16(rr[nt][t * 8 + 0], rr[nt][t * 8 + 1]);
                w.y = cvt_pk_bf16(rr[nt][t * 8 + 2], rr[nt][t * 8 + 3]);
                w.z = cvt_pk_bf16(rr[nt][t * 8 + 4], rr[nt][t * 8 + 5]);
                w.w = cvt_pk_bf16(rr[nt][t * 8 + 6], rr[nt][t * 8 + 7]);
                pk[nt][t] = *reinterpret_cast<bf16x8*>(&w);
            }
        }
    };

    #pragma unroll
    for (int s = 0; s < 27; ++s) {
        __syncthreads();
        if (s + 1 < 27) issueA(s + 1, (s + 1) & 1);
        const int fn = s % 9;
        if (fn == 0) phiInit(s / 9);
        else phiRbf(fn != 1);

        const char* Ab = smem + (s & 1) * 12288;
        #pragma unroll
        for (int mt = 0; mt < 3; ++mt) {
            const char* fb = Ab + mt * 4096 + lane * 16;
            bf16x8 b0h = *reinterpret_cast<const bf16x8*>(fb);
            bf16x8 b0l = *reinterpret_cast<const bf16x8*>(fb + 1024);
            bf16x8 b1h = *reinterpret_cast<const bf16x8*>(fb + 2048);
            bf16x8 b1l = *reinterpret_cast<const bf16x8*>(fb + 3072);
            #pragma unroll
            for (int nt = 0; nt < 2; ++nt) {
                acc[nt][mt] = MFMA32(pk[nt][0], b0h, acc[nt][mt]);
                acc[nt][mt] = MFMA32(pk[nt][0], b0l, acc[nt][mt]);
                acc[nt][mt] = MFMA32(pk[nt][1], b1h, acc[nt][mt]);
                acc[nt][mt] = MFMA32(pk[nt][1], b1l, acc[nt][mt]);
            }
        }
    }

    // ---- epilogue: D[p][m]; lane holds m = mt*32 + cl, p = base + (r&3)+8*(r>>2)+4*kg
    if (MODE == 0) {
        #pragma unroll
        for (int nt = 0; nt < 2; ++nt)
            #pragma unroll
            for (int r = 0; r < 16; ++r) {
                int p = n0 + wid * 64 + nt * 32 + (r & 3) + 8 * (r >> 2) + 4 * kg;
                int w = p / 17, l = p - w * 17;
                float* dst = out + (size_t)w * 4896 + l * 288 + mb * 96 + cl;
                dst[0]  = acc[nt][0][r];
                dst[32] = acc[nt][1][r];
                dst[64] = acc[nt][2][r];
            }
    } else {
        #pragma unroll
        for (int nt = 0; nt < 2; ++nt)
            #pragma unroll
            for (int r = 0; r < 16; ++r) {
                int p = n0 + wid * 64 + nt * 32 + (r & 3) + 8 * (r >> 2) + 4 * kg;
                float* dst = out + (size_t)p * 192 + mb * 96 + cl;
                dst[0]  = acc[nt][0][r];
                dst[32] = acc[nt][1][r];
                dst[64] = acc[nt][2][r];
            }
    }
}

// ============ kernel B: W = A-operand from LDS, phi staged in LDS (R9) =======
// L3 only: 96 rows x 128 cols, 4 waves, wave = 32-col tile x 3 mt.
// LDS: A dbuf 24 KiB + phi dbuf 16 KiB. Direct out[b][96][1024] stores.
__global__ __launch_bounds__(256, 4)
void kan_mfma_fmap(const float* __restrict__ xin,
                   const unsigned short* __restrict__ Wf, float* __restrict__ out)
{
    __shared__ __align__(16) char smem[40960];
    char* sA = smem;             // 2*12 KiB
    char* sB = smem + 24576;     // 2*8 KiB

    const int tid = threadIdx.x, lane = tid & 63, wid = tid >> 6;

    int xcd = blockIdx.x & 7;
    int n0 = (xcd * 128 + (blockIdx.x >> 3)) * 128;

    auto issueA = [&](int s, int buf) {
        #pragma unroll
        for (int c0 = 0; c0 < 3; ++c0) {
            int c = wid + c0 * 4;
            const unsigned short* src = Wf + ((size_t)s * 12 + c) * 512 + lane * 8;
            GLD_LDS16(src, sA + (buf * 12 + c) * 1024);
        }
    };
    issueA(0, 0);

    const int ct = tid & 127, kgp = tid >> 7;
    const int lane_in = kgp * 32 + (ct & 31);
    const int p = n0 + ct;
    const float* gbase = xin + (size_t)(p >> 10) * 98304 + (p & 1023);

    f32x16 acc[3];
    #pragma unroll
    for (int mt = 0; mt < 3; ++mt)
        #pragma unroll
        for (int r = 0; r < 16; ++r) acc[mt][r] = 0.f;

    float rr[16], du[16];

    auto phiInit = [&](int cg, char* d0, char* d1) {
        float ph[16];
        #pragma unroll
        for (int t = 0; t < 2; ++t)
            #pragma unroll
            for (int j = 0; j < 8; ++j) {
                int q = t * 8 + j;
                float xv = gbase[(size_t)(cg * 32 + t * 16 + kgp * 8 + j) * 1024];
                ph[q] = __fdividef(xv, 1.f + __expf(-xv));
                float a = fmaf(xv, 1.75f, 3.5f);
                rr[q] = __expf(-a * a);
                du[q] = __expf(fminf(fmaf(a, 2.f, -1.f), 80.f));
            }
        uint4 w0, w1;
        w0.x = cvt_pk_bf16(ph[0], ph[1]);  w0.y = cvt_pk_bf16(ph[2], ph[3]);
        w0.z = cvt_pk_bf16(ph[4], ph[5]);  w0.w = cvt_pk_bf16(ph[6], ph[7]);
        w1.x = cvt_pk_bf16(ph[8], ph[9]);  w1.y = cvt_pk_bf16(ph[10], ph[11]);
        w1.z = cvt_pk_bf16(ph[12], ph[13]); w1.w = cvt_pk_bf16(ph[14], ph[15]);
        *reinterpret_cast<uint4*>(d0) = w0;
        *reinterpret_cast<uint4*>(d1) = w1;
    };
    auto phiRbf = [&](bool upd, char* d0, char* d1) {
        if (upd) {
            #pragma unroll
            for (int q = 0; q < 16; ++q) { rr[q] *= du[q]; du[q] *= 0.1353352832366127f; }
        }
        uint4 w0, w1;
        w0.x = cvt_pk_bf16(rr[0], rr[1]);  w0.y = cvt_pk_bf16(rr[2], rr[3]);
        w0.z = cvt_pk_bf16(rr[4], rr[5]);  w0.w = cvt_pk_bf16(rr[6], rr[7]);
        w1.x = cvt_pk_bf16(rr[8], rr[9]);  w1.y = cvt_pk_bf16(rr[10], rr[11]);
        w1.z = cvt_pk_bf16(rr[12], rr[13]); w1.w = cvt_pk_bf16(rr[14], rr[15]);
        *reinterpret_cast<uint4*>(d0) = w0;
        *reinterpret_cast<uint4*>(d1) = w1;
    };

    phiInit(0, sB + (ct >> 5) * 1024 + lane_in * 16,
               sB + (4 + (ct >> 5)) * 1024 + lane_in * 16);

    #pragma unroll
    for (int s = 0; s < 27; ++s) {
        int sb = s & 1;
        __syncthreads();
        if (s + 1 < 27) issueA(s + 1, (s + 1) & 1);
        {
            const char* Ab = sA + sb * 12288;
            const char* Bb = sB + sb * 8192;
            bf16x8 b0 = *reinterpret_cast<const bf16x8*>(Bb + wid * 1024 + lane * 16);
            bf16x8 b1 = *reinterpret_cast<const bf16x8*>(Bb + (4 + wid) * 1024 + lane * 16);
            #pragma unroll
            for (int mt = 0; mt < 3; ++mt) {
                const char* fb = Ab + mt * 4096 + lane * 16;
                bf16x8 a0 = *reinterpret_cast<const bf16x8*>(fb);
                bf16x8 a1 = *reinterpret_cast<const bf16x8*>(fb + 1024);
                bf16x8 a2 = *reinterpret_cast<const bf16x8*>(fb + 2048);
                bf16x8 a3 = *reinterpret_cast<const bf16x8*>(fb + 3072);
                acc[mt] = MFMA32(a0, b0, acc[mt]);
                acc[mt] = MFMA32(a1, b0, acc[mt]);
                acc[mt] = MFMA32(a2, b1, acc[mt]);
                acc[mt] = MFMA32(a3, b1, acc[mt]);
            }
        }
        if (s + 1 < 27) {
            char* d0 = sB + ((s + 1) & 1) * 8192 + (ct >> 5) * 1024 + lane_in * 16;
            int fn = (s + 1) % 9;
            if (fn == 0) phiInit((s + 1) / 9, d0, d0 + 4096);
            else phiRbf(fn != 1, d0, d0 + 4096);
        }
    }

    // C/D 32x32: col = lane&31, row = (r&3)+8*(r>>2)+4*(lane>>5)
    const int colL = n0 + wid * 32 + (lane & 31);
    #pragma unroll
    for (int mt = 0; mt < 3; ++mt) {
        #pragma unroll
        for (int r = 0; r < 16; ++r) {
            int row = mt * 32 + (r & 3) + 8 * (r >> 2) + 4 * (lane >> 5);
            out[(size_t)(colL >> 10) * 98304 + (size_t)row * 1024 + (colL & 1023)] = acc[mt][r];
        }
    }
}

// ============ window feature-attention + fused LN/GELU =======================
// qkv window-major; gt rows are block-local -> LN+GELU in-block, write hh.
__global__ __launch_bounds__(256)
void attn1(const float* __restrict__ qkv, const float* __restrict__ lng,
           const float* __restrict__ lnb, float* __restrict__ gf,
           float* __restrict__ hh)
{
    __shared__ float sw[17][288];
    __shared__ float sa[3][32][33];
    __shared__ float sgt[3][32];
    const int w = blockIdx.x, tid = threadIdx.x;

    const float4* src = reinterpret_cast<const float4*>(qkv + (size_t)w * 4896);
    float4* dstl = reinterpret_cast<float4*>(&sw[0][0]);
    for (int e = tid; e < 1224; e += 256) dstl[e] = src[e];
    __syncthreads();

    for (int e = tid; e < 3072; e += 256) {
        int h = e >> 10, r = e & 1023, i = r >> 5, j = r & 31;
        float s = 0.f;
        #pragma unroll
        for (int l = 0; l < 17; ++l) s += sw[l][h * 32 + i] * sw[l][96 + h * 32 + j];
        sa[h][i][j] = s * SCALE;
    }
    __syncthreads();
    if (tid < 96) {
        int h = tid >> 5, i = tid & 31;
        float m = -1e30f;
        for (int j = 0; j < 32; ++j) m = fmaxf(m, sa[h][i][j]);
        float sum = 0.f;
        for (int j = 0; j < 32; ++j) { float e_ = __expf(sa[h][i][j] - m); sa[h][i][j] = e_; sum += e_; }
        float inv = 1.f / sum;
        for (int j = 0; j < 32; ++j) sa[h][i][j] *= inv;
    }
    __syncthreads();
    const int b = w >> 6, wl = w & 63;
    for (int e = tid; e < 1632; e += 256) {
        int h = e / 544, r = e - h * 544, l = r >> 5, i = r & 31;
        float s = 0.f;
        #pragma unroll
        for (int j = 0; j < 32; ++j) s += sa[h][i][j] * sw[l][192 + h * 32 + j];
        if (l == 0) sgt[h][i] = s;
        else        gf[((((size_t)b * 3 + h) * 64 + wl) * 16 + (l - 1)) * 32 + i] = s;
    }
    __syncthreads();
    if (tid < 96) {
        int h = tid >> 5, d = tid & 31;
        float xv = sgt[h][d];
        float s1 = xv, s2 = xv * xv;
        #pragma unroll
        for (int m = 16; m >= 1; m >>= 1) { s1 += __shfl_xor(s1, m, 32); s2 += __shfl_xor(s2, m, 32); }
        float mu = s1 * (1.f / 32.f);
        float var = s2 * (1.f / 32.f) - mu * mu;
        float hv = (xv - mu) * rsqrtf(var + EPS) * lng[d] + lnb[d];
        float g = 0.5f * hv * (1.f + erff(hv * 0.70710678118654752f));
        hh[((size_t)b * 96 + h * 32 + d) * 64 + wl] = g;
    }
}

// ============ fused window-token attention: dots+softmax+agg+scatter =========
// One block per bh (384). qk col-major [p][192]. Loops the 4 ct gf tiles.
__global__ __launch_bounds__(256)
void attn2(const float* __restrict__ qk, const float* __restrict__ gf,
           float* __restrict__ fmap)
{
    int bh = blockIdx.x;
    int b = bh / 3, h = bh - b * 3;
    __shared__ float swq[64][33];
    __shared__ float swk[64][33];
    __shared__ float sa[64][65];
    __shared__ float sg[64][129];
    int tid = threadIdx.x;
    for (int e = tid; e < 2048; e += 256) {
        int i = e >> 5, d = e & 31;
        const float* row = qk + ((size_t)b * 64 + i) * 192 + h * 64;
        swq[i][d] = row[d] * SCALE;
        swk[i][d] = row[32 + d];
    }
    __syncthreads();
    for (int e = tid; e < 4096; e += 256) {
        int i = e >> 6, j = e & 63;
        float s = 0.f;
        #pragma unroll
        for (int d = 0; d < 32; ++d) s += swq[i][d] * swk[j][d];
        sa[i][j] = s;
    }
    __syncthreads();
    if (tid < 64) {
        float m = -1e30f;
        for (int j = 0; j < 64; ++j) m = fmaxf(m, sa[tid][j]);
        float sum = 0.f;
        for (int j = 0; j < 64; ++j) { float e_ = __expf(sa[tid][j] - m); sa[tid][j] = e_; sum += e_; }
        float inv = 1.f / sum;
        for (int j = 0; j < 64; ++j) sa[tid][j] *= inv;
    }
    __syncthreads();

    const int txc = tid & 31, tyi = tid >> 5;
    for (int ct = 0; ct < 4; ++ct) {
        for (int e = tid; e < 8192; e += 256) {
            int j = e >> 7, c = e & 127;
            sg[j][c] = gf[((size_t)bh * 64 + j) * 512 + ct * 128 + c];
        }
        __syncthreads();
        float acc[8][4];
        #pragma unroll
        for (int ii = 0; ii < 8; ++ii)
            #pragma unroll
            for (int c = 0; c < 4; ++c) acc[ii][c] = 0.f;
        for (int j = 0; j < 64; ++j) {
            float g0[4];
            #pragma unroll
            for (int c = 0; c < 4; ++c) g0[c] = sg[j][txc + c * 32];
            #pragma unroll
            for (int ii = 0; ii < 8; ++ii) {
                float a = sa[tyi + ii * 8][j];
                #pragma unroll
                for (int c = 0; c < 4; ++c) acc[ii][c] += a * g0[c];
            }
        }
        __syncthreads();
        #pragma unroll
        for (int ii = 0; ii < 8; ++ii)
            #pragma unroll
            for (int c = 0; c < 4; ++c)
                sg[tyi + ii * 8][txc + c * 32] = acc[ii][c];
        __syncthreads();
        for (int e = tid; e < 8192; e += 256) {
            int d = e >> 8;
            int nx = (e >> 5) & 7;
            int cp = e & 31;
            int ny = cp >> 2, gy = cp & 3;
            float v = sg[nx * 8 + ny][gy * 32 + d];
            fmap[(((size_t)b * 96 + h * 32 + d) * 32 + nx * 4 + ct) * 32 + cp] = v;
        }
        __syncthreads();
    }
}

// -----------------------------------------------------------------------------
extern "C" void kernel_launch(void* const* d_in, const int* in_sizes, int n_in,
                              void* d_out, int out_size, void* d_ws, size_t ws_size,
                              hipStream_t stream)
{
    const float* x      = (const float*)d_in[0];
    const float* tok    = (const float*)d_in[1];
    const float* qkv_wb = (const float*)d_in[2];
    const float* qkv_ws = (const float*)d_in[3];
    const float* lng    = (const float*)d_in[4];
    const float* lnb    = (const float*)d_in[5];
    const float* gt_wb  = (const float*)d_in[6];
    const float* gt_ws  = (const float*)d_in[7];
    const float* out_wb = (const float*)d_in[8];
    const float* out_ws = (const float*)d_in[9];
    float* out = (float*)d_out;
    float* ws  = (float*)d_ws;

    const size_t OFF_QKV   = 0;            // 40,108,032 floats (window-major)
    const size_t OFF_FMAP  = 0;            // reuses dead qkv region
    const size_t OFF_WF2   = 40108032;     // 165,888 floats
    const size_t OFF_GT    = OFF_WF2 + 165888;   // (unused; kept for layout)
    const size_t OFF_GF    = OFF_GT + 786432;
    const size_t OFF_HH    = OFF_GF + 12582912;
    const size_t OFF_QK    = OFF_HH + 786432;   // col-major [8192][192]
    const size_t OFF_WF1   = OFF_QK + 1572864;  // 248,832 floats
    const size_t OFF_WF3   = OFF_WF1 + 248832;  // 82,944 floats
    const size_t TOTAL     = OFF_WF3 + 82944;   // 56,334,336 floats
    if (ws_size < TOTAL * sizeof(float)) return;

    unsigned short* wf1 = (unsigned short*)(ws + OFF_WF1);
    unsigned short* wf2 = (unsigned short*)(ws + OFF_WF2);
    unsigned short* wf3 = (unsigned short*)(ws + OFF_WF3);

    prep_frag32<<<243, 256, 0, stream>>>(qkv_wb, qkv_ws, wf1, 9);
    prep_frag32<<<162, 256, 0, stream>>>(gt_wb,  gt_ws,  wf2, 6);
    prep_frag32<<< 81, 256, 0, stream>>>(out_wb, out_ws, wf3, 3);

    kan_mfma<9, 0><<<1632, 256, 0, stream>>>(x, tok, wf1, ws + OFF_QKV);
    attn1<<<8192, 256, 0, stream>>>(ws + OFF_QKV, lng, lnb, ws + OFF_GF, ws + OFF_HH);
    kan_mfma<6, 2><<<64, 256, 0, stream>>>(ws + OFF_HH, nullptr, wf2, ws + OFF_QK);
    attn2<<<384, 256, 0, stream>>>(ws + OFF_QK, ws + OFF_GF, ws + OFF_FMAP);
    kan_mfma_fmap<<<1024, 256, 0, stream>>>(ws + OFF_FMAP, wf3, out);
}

// Round 20
// 411.161 us; speedup vs baseline: 1.1125x; 1.1094x over previous
//
#include <hip/hip_runtime.h>
#include <cstddef>

#define SCALE 0.17677669529663687f
#define EPS 1e-5f

typedef __attribute__((ext_vector_type(8))) __bf16 bf16x8;
typedef __attribute__((ext_vector_type(16))) float f32x16;
typedef __attribute__((ext_vector_type(8))) unsigned short ushort8;

__device__ __forceinline__ unsigned short f2bf(float f) {
    unsigned u = __float_as_uint(f);
    return (unsigned short)((u + 0x7fffu + ((u >> 16) & 1u)) >> 16);
}
__device__ __forceinline__ float bf2f(unsigned short h) {
    return __uint_as_float(((unsigned)h) << 16);
}
__device__ __forceinline__ unsigned cvt_pk_bf16(float a, float b) {
    unsigned r;
    asm("v_cvt_pk_bf16_f32 %0, %1, %2" : "=v"(r) : "v"(a), "v"(b));
    return r;
}

#define MFMA32(a, b, c) __builtin_amdgcn_mfma_f32_32x32x16_bf16(a, b, c, 0, 0, 0)

#define GLD_LDS16(gsrc, ldst) \
    __builtin_amdgcn_global_load_lds((const __attribute__((address_space(1))) void*)(gsrc), \
                                     (__attribute__((address_space(3))) void*)(ldst), 16, 0, 0)

// ============ prep (merged): W -> 32x32x16 MFMA fragments, split hi/lo =======
// K-order (cg-major): step s = cg*9+f; f=0 silu, f=1..8 rbf center f-1.
// fragIdx = ((s*MTT + mt)*2 + kf)*2 + hl. Frag 1024B lane-linear:
// lane l holds W row m = mt*32 + (l&31), k-slot j -> ch c = cg*32 + kf*16 + (l>>5)*8 + j.
// Blocks [0,243) -> Wf1 (MTT 9); [243,405) -> Wf2 (MTT 6); [405,486) -> Wf3 (MTT 3).
__global__ __launch_bounds__(256)
void prep_all(const float* __restrict__ wb1, const float* __restrict__ ws1, unsigned short* __restrict__ Wf1,
              const float* __restrict__ wb2, const float* __restrict__ ws2, unsigned short* __restrict__ Wf2,
              const float* __restrict__ wb3, const float* __restrict__ ws3, unsigned short* __restrict__ Wf3)
{
    int b = blockIdx.x;
    const float* wb; const float* wsp; unsigned short* Wf; int MTT, idx;
    if (b < 243)      { wb = wb1; wsp = ws1; Wf = Wf1; MTT = 9; idx = b * 256 + threadIdx.x; }
    else if (b < 405) { wb = wb2; wsp = ws2; Wf = Wf2; MTT = 6; idx = (b - 243) * 256 + threadIdx.x; }
    else              { wb = wb3; wsp = ws3; Wf = Wf3; MTT = 3; idx = (b - 405) * 256 + threadIdx.x; }
    int total = 27 * MTT * 4 * 64;
    if (idx >= total) return;
    int lane = idx & 63;
    int t = idx >> 6;
    int hl = t & 1, kf = (t >> 1) & 1;
    int mt = (t >> 2) % MTT, s = (t >> 2) / MTT;
    int cg = s / 9, f = s - cg * 9;
    int m = mt * 32 + (lane & 31);
    int kg = lane >> 5;
    ushort8 v;
    #pragma unroll
    for (int j = 0; j < 8; ++j) {
        int c = cg * 32 + kf * 16 + kg * 8 + j;
        float w = (f == 0) ? wb[m * 96 + c] : wsp[(m * 96 + c) * 8 + (f - 1)];
        unsigned short hi = f2bf(w);
        v[j] = hl ? f2bf(w - bf2f(hi)) : hi;
    }
    *reinterpret_cast<ushort8*>(Wf + (size_t)t * 512 + lane * 8) = v;
}

// ============ kernel A: phi = A operand, W = B in LDS (R16 verified) =========
// Block: 96 rows (mb) x 256 cols. 4 waves; wave = 64 cols (2 tiles) x 3 mt.
// LDS dbuf 24 KiB; 2 blocks/CU (208 unified regs; structural, R11/R12/R16).
// R17 lesson: qbuf+14-barriers regressed (+14us, FETCH +23MB) -> dbuf kept.
// MODE 0: windowed gather (L1), out window-major qkv[w*4896 + l*288 + m]
// MODE 2: lin64 gather   (L2), out col-major qk[p*192 + m]
template<int MTT, int MODE>
__global__ __launch_bounds__(256, 2)
void kan_mfma(const float* __restrict__ xin, const float* __restrict__ token,
              const unsigned short* __restrict__ Wf, float* __restrict__ out)
{
    __shared__ __align__(16) char smem[2 * 12 * 1024];

    const int tid = threadIdx.x, lane = tid & 63, wid = tid >> 6;
    const int kg = lane >> 5, cl = lane & 31;

    int n0, mb;
    if (MODE == 0) {
        int xcd = blockIdx.x & 7, idx = blockIdx.x >> 3;   // 204 per XCD
        int nloc = idx / 3; mb = idx - nloc * 3;
        n0 = (xcd * 68 + nloc) * 256;
    } else {
        mb = blockIdx.x & 1; n0 = (blockIdx.x >> 1) * 256;
    }

    auto issueA = [&](int s, int buf) {
        #pragma unroll
        for (int c0 = 0; c0 < 3; ++c0) {
            int c = wid + c0 * 4;
            const unsigned short* src = Wf + ((size_t)s * MTT * 4 + mb * 12 + c) * 512 + lane * 8;
            GLD_LDS16(src, smem + (buf * 12 + c) * 1024);
        }
    };
    issueA(0, 0);

    // ---- per-thread: two columns (A rows) ----------------------------------
    const float* gbv[2];
    int gsv[2];
    #pragma unroll
    for (int nt = 0; nt < 2; ++nt) {
        int p = n0 + wid * 64 + nt * 32 + cl;
        if (MODE == 0) {
            int w = p / 17, l = p - w * 17;
            if (l == 0) { gbv[nt] = token; gsv[nt] = 1; }
            else {
                int b = w >> 6, wl = w & 63;
                int wx = wl >> 3, wy = wl & 7;
                int jj = l - 1, gx = jj >> 2, gy = jj & 3;
                gbv[nt] = xin + (size_t)b * 98304 + (wx * 4 + gx) * 32 + wy * 4 + gy;
                gsv[nt] = 1024;
            }
        } else {
            gbv[nt] = xin + (size_t)(p >> 6) * 6144 + (p & 63);
            gsv[nt] = 64;
        }
    }

    f32x16 acc[2][3];
    #pragma unroll
    for (int nt = 0; nt < 2; ++nt)
        #pragma unroll
        for (int mt = 0; mt < 3; ++mt)
            #pragma unroll
            for (int r = 0; r < 16; ++r) acc[nt][mt][r] = 0.f;

    float rr[2][16], du[2][16];
    bf16x8 pk[2][2];

    auto phiInit = [&](int cg) {
        #pragma unroll
        for (int nt = 0; nt < 2; ++nt) {
            float ph[16];
            #pragma unroll
            for (int t = 0; t < 2; ++t)
                #pragma unroll
                for (int j = 0; j < 8; ++j) {
                    int q = t * 8 + j;
                    float xv = gbv[nt][(size_t)(cg * 32 + t * 16 + kg * 8 + j) * gsv[nt]];
                    ph[q] = __fdividef(xv, 1.f + __expf(-xv));
                    float a = fmaf(xv, 1.75f, 3.5f);
                    rr[nt][q] = __expf(-a * a);
                    du[nt][q] = __expf(fminf(fmaf(a, 2.f, -1.f), 80.f));
                }
            #pragma unroll
            for (int t = 0; t < 2; ++t) {
                uint4 w;
                w.x = cvt_pk_bf16(ph[t * 8 + 0], ph[t * 8 + 1]);
                w.y = cvt_pk_bf16(ph[t * 8 + 2], ph[t * 8 + 3]);
                w.z = cvt_pk_bf16(ph[t * 8 + 4], ph[t * 8 + 5]);
                w.w = cvt_pk_bf16(ph[t * 8 + 6], ph[t * 8 + 7]);
                pk[nt][t] = *reinterpret_cast<bf16x8*>(&w);
            }
        }
    };
    auto phiRbf = [&](bool upd) {
        #pragma unroll
        for (int nt = 0; nt < 2; ++nt) {
            if (upd) {
                #pragma unroll
                for (int q = 0; q < 16; ++q) { rr[nt][q] *= du[nt][q]; du[nt][q] *= 0.1353352832366127f; }
            }
            #pragma unroll
            for (int t = 0; t < 2; ++t) {
                uint4 w;
                w.x = cvt_pk_bf16(rr[nt][t * 8 + 0], rr[nt][t * 8 + 1]);
                w.y = cvt_pk_bf16(rr[nt][t * 8 + 2], rr[nt][t * 8 + 3]);
                w.z = cvt_pk_bf16(rr[nt][t * 8 + 4], rr[nt][t * 8 + 5]);
                w.w = cvt_pk_bf16(rr[nt][t * 8 + 6], rr[nt][t * 8 + 7]);
                pk[nt][t] = *reinterpret_cast<bf16x8*>(&w);
            }
        }
    };

    #pragma unroll
    for (int s = 0; s < 27; ++s) {
        __syncthreads();
        if (s + 1 < 27) issueA(s + 1, (s + 1) & 1);
        const int fn = s % 9;
        if (fn == 0) phiInit(s / 9);
        else phiRbf(fn != 1);

        const char* Ab = smem + (s & 1) * 12288;
        #pragma unroll
        for (int mt = 0; mt < 3; ++mt) {
            const char* fb = Ab + mt * 4096 + lane * 16;
            bf16x8 b0h = *reinterpret_cast<const bf16x8*>(fb);
            bf16x8 b0l = *reinterpret_cast<const bf16x8*>(fb + 1024);
            bf16x8 b1h = *reinterpret_cast<const bf16x8*>(fb + 2048);
            bf16x8 b1l = *reinterpret_cast<const bf16x8*>(fb + 3072);
            #pragma unroll
            for (int nt = 0; nt < 2; ++nt) {
                acc[nt][mt] = MFMA32(pk[nt][0], b0h, acc[nt][mt]);
                acc[nt][mt] = MFMA32(pk[nt][0], b0l, acc[nt][mt]);
                acc[nt][mt] = MFMA32(pk[nt][1], b1h, acc[nt][mt]);
                acc[nt][mt] = MFMA32(pk[nt][1], b1l, acc[nt][mt]);
            }
        }
    }

    // ---- epilogue: D[p][m]; lane holds m = mt*32 + cl, p = base + (r&3)+8*(r>>2)+4*kg
    if (MODE == 0) {
        #pragma unroll
        for (int nt = 0; nt < 2; ++nt)
            #pragma unroll
            for (int r = 0; r < 16; ++r) {
                int p = n0 + wid * 64 + nt * 32 + (r & 3) + 8 * (r >> 2) + 4 * kg;
                int w = p / 17, l = p - w * 17;
                float* dst = out + (size_t)w * 4896 + l * 288 + mb * 96 + cl;
                dst[0]  = acc[nt][0][r];
                dst[32] = acc[nt][1][r];
                dst[64] = acc[nt][2][r];
            }
    } else {
        #pragma unroll
        for (int nt = 0; nt < 2; ++nt)
            #pragma unroll
            for (int r = 0; r < 16; ++r) {
                int p = n0 + wid * 64 + nt * 32 + (r & 3) + 8 * (r >> 2) + 4 * kg;
                float* dst = out + (size_t)p * 192 + mb * 96 + cl;
                dst[0]  = acc[nt][0][r];
                dst[32] = acc[nt][1][r];
                dst[64] = acc[nt][2][r];
            }
    }
}

// ============ kernel B: W = A-operand from LDS, phi staged in LDS (R9) =======
// L3 only: 96 rows x 128 cols, 4 waves, wave = 32-col tile x 3 mt.
// LDS: A dbuf 24 KiB + phi dbuf 16 KiB. Direct out[b][96][1024] stores.
__global__ __launch_bounds__(256, 4)
void kan_mfma_fmap(const float* __restrict__ xin,
                   const unsigned short* __restrict__ Wf, float* __restrict__ out)
{
    __shared__ __align__(16) char smem[40960];
    char* sA = smem;             // 2*12 KiB
    char* sB = smem + 24576;     // 2*8 KiB

    const int tid = threadIdx.x, lane = tid & 63, wid = tid >> 6;

    int xcd = blockIdx.x & 7;
    int n0 = (xcd * 128 + (blockIdx.x >> 3)) * 128;

    auto issueA = [&](int s, int buf) {
        #pragma unroll
        for (int c0 = 0; c0 < 3; ++c0) {
            int c = wid + c0 * 4;
            const unsigned short* src = Wf + ((size_t)s * 12 + c) * 512 + lane * 8;
            GLD_LDS16(src, sA + (buf * 12 + c) * 1024);
        }
    };
    issueA(0, 0);

    const int ct = tid & 127, kgp = tid >> 7;
    const int lane_in = kgp * 32 + (ct & 31);
    const int p = n0 + ct;
    const float* gbase = xin + (size_t)(p >> 10) * 98304 + (p & 1023);

    f32x16 acc[3];
    #pragma unroll
    for (int mt = 0; mt < 3; ++mt)
        #pragma unroll
        for (int r = 0; r < 16; ++r) acc[mt][r] = 0.f;

    float rr[16], du[16];

    auto phiInit = [&](int cg, char* d0, char* d1) {
        float ph[16];
        #pragma unroll
        for (int t = 0; t < 2; ++t)
            #pragma unroll
            for (int j = 0; j < 8; ++j) {
                int q = t * 8 + j;
                float xv = gbase[(size_t)(cg * 32 + t * 16 + kgp * 8 + j) * 1024];
                ph[q] = __fdividef(xv, 1.f + __expf(-xv));
                float a = fmaf(xv, 1.75f, 3.5f);
                rr[q] = __expf(-a * a);
                du[q] = __expf(fminf(fmaf(a, 2.f, -1.f), 80.f));
            }
        uint4 w0, w1;
        w0.x = cvt_pk_bf16(ph[0], ph[1]);  w0.y = cvt_pk_bf16(ph[2], ph[3]);
        w0.z = cvt_pk_bf16(ph[4], ph[5]);  w0.w = cvt_pk_bf16(ph[6], ph[7]);
        w1.x = cvt_pk_bf16(ph[8], ph[9]);  w1.y = cvt_pk_bf16(ph[10], ph[11]);
        w1.z = cvt_pk_bf16(ph[12], ph[13]); w1.w = cvt_pk_bf16(ph[14], ph[15]);
        *reinterpret_cast<uint4*>(d0) = w0;
        *reinterpret_cast<uint4*>(d1) = w1;
    };
    auto phiRbf = [&](bool upd, char* d0, char* d1) {
        if (upd) {
            #pragma unroll
            for (int q = 0; q < 16; ++q) { rr[q] *= du[q]; du[q] *= 0.1353352832366127f; }
        }
        uint4 w0, w1;
        w0.x = cvt_pk_bf16(rr[0], rr[1]);  w0.y = cvt_pk_bf16(rr[2], rr[3]);
        w0.z = cvt_pk_bf16(rr[4], rr[5]);  w0.w = cvt_pk_bf16(rr[6], rr[7]);
        w1.x = cvt_pk_bf16(rr[8], rr[9]);  w1.y = cvt_pk_bf16(rr[10], rr[11]);
        w1.z = cvt_pk_bf16(rr[12], rr[13]); w1.w = cvt_pk_bf16(rr[14], rr[15]);
        *reinterpret_cast<uint4*>(d0) = w0;
        *reinterpret_cast<uint4*>(d1) = w1;
    };

    phiInit(0, sB + (ct >> 5) * 1024 + lane_in * 16,
               sB + (4 + (ct >> 5)) * 1024 + lane_in * 16);

    #pragma unroll
    for (int s = 0; s < 27; ++s) {
        int sb = s & 1;
        __syncthreads();
        if (s + 1 < 27) issueA(s + 1, (s + 1) & 1);
        {
            const char* Ab = sA + sb * 12288;
            const char* Bb = sB + sb * 8192;
            bf16x8 b0 = *reinterpret_cast<const bf16x8*>(Bb + wid * 1024 + lane * 16);
            bf16x8 b1 = *reinterpret_cast<const bf16x8*>(Bb + (4 + wid) * 1024 + lane * 16);
            #pragma unroll
            for (int mt = 0; mt < 3; ++mt) {
                const char* fb = Ab + mt * 4096 + lane * 16;
                bf16x8 a0 = *reinterpret_cast<const bf16x8*>(fb);
                bf16x8 a1 = *reinterpret_cast<const bf16x8*>(fb + 1024);
                bf16x8 a2 = *reinterpret_cast<const bf16x8*>(fb + 2048);
                bf16x8 a3 = *reinterpret_cast<const bf16x8*>(fb + 3072);
                acc[mt] = MFMA32(a0, b0, acc[mt]);
                acc[mt] = MFMA32(a1, b0, acc[mt]);
                acc[mt] = MFMA32(a2, b1, acc[mt]);
                acc[mt] = MFMA32(a3, b1, acc[mt]);
            }
        }
        if (s + 1 < 27) {
            char* d0 = sB + ((s + 1) & 1) * 8192 + (ct >> 5) * 1024 + lane_in * 16;
            int fn = (s + 1) % 9;
            if (fn == 0) phiInit((s + 1) / 9, d0, d0 + 4096);
            else phiRbf(fn != 1, d0, d0 + 4096);
        }
    }

    // C/D 32x32: col = lane&31, row = (r&3)+8*(r>>2)+4*(lane>>5)
    const int colL = n0 + wid * 32 + (lane & 31);
    #pragma unroll
    for (int mt = 0; mt < 3; ++mt) {
        #pragma unroll
        for (int r = 0; r < 16; ++r) {
            int row = mt * 32 + (r & 3) + 8 * (r >> 2) + 4 * (lane >> 5);
            out[(size_t)(colL >> 10) * 98304 + (size_t)row * 1024 + (colL & 1023)] = acc[mt][r];
        }
    }
}

// ============ window feature-attention + fused LN/GELU =======================
// qkv window-major. Register-blocked QK^T (4 j per thread) and PV (4 l per
// thread): q/sw-row reads become broadcasts, halving LDS read count.
__global__ __launch_bounds__(256)
void attn1(const float* __restrict__ qkv, const float* __restrict__ lng,
           const float* __restrict__ lnb, float* __restrict__ gf,
           float* __restrict__ hh)
{
    __shared__ float sw[17][288];
    __shared__ float sa[3][32][33];
    __shared__ float sgt[3][32];
    const int w = blockIdx.x, tid = threadIdx.x;

    const float4* src = reinterpret_cast<const float4*>(qkv + (size_t)w * 4896);
    float4* dstl = reinterpret_cast<float4*>(&sw[0][0]);
    for (int e = tid; e < 1224; e += 256) dstl[e] = src[e];
    __syncthreads();

    // QK^T: thread -> (h, i, j0..j0+3); 768 = 3 iter/thread
    for (int e = tid; e < 768; e += 256) {
        int h = e >> 8, r = e & 255, i = r >> 3, j0 = (r & 7) * 4;
        float a0 = 0.f, a1 = 0.f, a2 = 0.f, a3 = 0.f;
        #pragma unroll
        for (int l = 0; l < 17; ++l) {
            float q = sw[l][h * 32 + i];
            const float* kr = &sw[l][96 + h * 32 + j0];
            a0 += q * kr[0]; a1 += q * kr[1]; a2 += q * kr[2]; a3 += q * kr[3];
        }
        sa[h][i][j0 + 0] = a0 * SCALE;
        sa[h][i][j0 + 1] = a1 * SCALE;
        sa[h][i][j0 + 2] = a2 * SCALE;
        sa[h][i][j0 + 3] = a3 * SCALE;
    }
    __syncthreads();
    if (tid < 96) {
        int h = tid >> 5, i = tid & 31;
        float m = -1e30f;
        for (int j = 0; j < 32; ++j) m = fmaxf(m, sa[h][i][j]);
        float sum = 0.f;
        for (int j = 0; j < 32; ++j) { float e_ = __expf(sa[h][i][j] - m); sa[h][i][j] = e_; sum += e_; }
        float inv = 1.f / sum;
        for (int j = 0; j < 32; ++j) sa[h][i][j] *= inv;
    }
    __syncthreads();
    const int b = w >> 6, wl = w & 63;
    // PV: thread -> (h, lc, i) with l = lc*4..lc*4+3 (l<16); 384 items
    for (int e = tid; e < 384; e += 256) {
        int h = e >> 7, r = e & 127, lc = r >> 5, i = r & 31;
        int l0 = lc * 4;
        float a0 = 0.f, a1 = 0.f, a2 = 0.f, a3 = 0.f;
        #pragma unroll 8
        for (int j = 0; j < 32; ++j) {
            float a = sa[h][i][j];
            a0 += a * sw[l0 + 0][192 + h * 32 + j];
            a1 += a * sw[l0 + 1][192 + h * 32 + j];
            a2 += a * sw[l0 + 2][192 + h * 32 + j];
            a3 += a * sw[l0 + 3][192 + h * 32 + j];
        }
        size_t gbase = (((size_t)b * 3 + h) * 64 + wl) * 16;
        if (l0 == 0) sgt[h][i] = a0;
        else         gf[(gbase + (l0 - 1)) * 32 + i] = a0;
        gf[(gbase + l0 + 0) * 32 + i] = a1;
        gf[(gbase + l0 + 1) * 32 + i] = a2;
        gf[(gbase + l0 + 2) * 32 + i] = a3;
    }
    // tail l = 16
    if (tid < 96) {
        int h = tid >> 5, i = tid & 31;
        float s = 0.f;
        #pragma unroll 8
        for (int j = 0; j < 32; ++j) s += sa[h][i][j] * sw[16][192 + h * 32 + j];
        gf[((((size_t)b * 3 + h) * 64 + wl) * 16 + 15) * 32 + i] = s;
    }
    __syncthreads();
    if (tid < 96) {
        int h = tid >> 5, d = tid & 31;
        float xv = sgt[h][d];
        float s1 = xv, s2 = xv * xv;
        #pragma unroll
        for (int m = 16; m >= 1; m >>= 1) { s1 += __shfl_xor(s1, m, 32); s2 += __shfl_xor(s2, m, 32); }
        float mu = s1 * (1.f / 32.f);
        float var = s2 * (1.f / 32.f) - mu * mu;
        float hv = (xv - mu) * rsqrtf(var + EPS) * lng[d] + lnb[d];
        float g = 0.5f * hv * (1.f + erff(hv * 0.70710678118654752f));
        hh[((size_t)b * 96 + h * 32 + d) * 64 + wl] = g;
    }
}

// ============ fused window-token attention: dots+softmax+agg+scatter =========
// One block per bh (384). qk col-major [p][192]. Loops the 4 ct gf tiles.
__global__ __launch_bounds__(256)
void attn2(const float* __restrict__ qk, const float* __restrict__ gf,
           float* __restrict__ fmap)
{
    int bh = blockIdx.x;
    int b = bh / 3, h = bh - b * 3;
    __shared__ float swq[64][33];
    __shared__ float swk[64][33];
    __shared__ float sa[64][65];
    __shared__ float sg[64][129];
    int tid = threadIdx.x;
    for (int e = tid; e < 2048; e += 256) {
        int i = e >> 5, d = e & 31;
        const float* row = qk + ((size_t)b * 64 + i) * 192 + h * 64;
        swq[i][d] = row[d] * SCALE;
        swk[i][d] = row[32 + d];
    }
    __syncthreads();
    for (int e = tid; e < 4096; e += 256) {
        int i = e >> 6, j = e & 63;
        float s = 0.f;
        #pragma unroll
        for (int d = 0; d < 32; ++d) s += swq[i][d] * swk[j][d];
        sa[i][j] = s;
    }
    __syncthreads();
    if (tid < 64) {
        float m = -1e30f;
        for (int j = 0; j < 64; ++j) m = fmaxf(m, sa[tid][j]);
        float sum = 0.f;
        for (int j = 0; j < 64; ++j) { float e_ = __expf(sa[tid][j] - m); sa[tid][j] = e_; sum += e_; }
        float inv = 1.f / sum;
        for (int j = 0; j < 64; ++j) sa[tid][j] *= inv;
    }
    __syncthreads();

    const int txc = tid & 31, tyi = tid >> 5;
    for (int ct = 0; ct < 4; ++ct) {
        for (int e = tid; e < 8192; e += 256) {
            int j = e >> 7, c = e & 127;
            sg[j][c] = gf[((size_t)bh * 64 + j) * 512 + ct * 128 + c];
        }
        __syncthreads();
        float acc[8][4];
        #pragma unroll
        for (int ii = 0; ii < 8; ++ii)
            #pragma unroll
            for (int c = 0; c < 4; ++c) acc[ii][c] = 0.f;
        for (int j = 0; j < 64; ++j) {
            float g0[4];
            #pragma unroll
            for (int c = 0; c < 4; ++c) g0[c] = sg[j][txc + c * 32];
            #pragma unroll
            for (int ii = 0; ii < 8; ++ii) {
                float a = sa[tyi + ii * 8][j];
                #pragma unroll
                for (int c = 0; c < 4; ++c) acc[ii][c] += a * g0[c];
            }
        }
        __syncthreads();
        #pragma unroll
        for (int ii = 0; ii < 8; ++ii)
            #pragma unroll
            for (int c = 0; c < 4; ++c)
                sg[tyi + ii * 8][txc + c * 32] = acc[ii][c];
        __syncthreads();
        for (int e = tid; e < 8192; e += 256) {
            int d = e >> 8;
            int nx = (e >> 5) & 7;
            int cp = e & 31;
            int ny = cp >> 2, gy = cp & 3;
            float v = sg[nx * 8 + ny][gy * 32 + d];
            fmap[(((size_t)b * 96 + h * 32 + d) * 32 + nx * 4 + ct) * 32 + cp] = v;
        }
        __syncthreads();
    }
}

// -----------------------------------------------------------------------------
extern "C" void kernel_launch(void* const* d_in, const int* in_sizes, int n_in,
                              void* d_out, int out_size, void* d_ws, size_t ws_size,
                              hipStream_t stream)
{
    const float* x      = (const float*)d_in[0];
    const float* tok    = (const float*)d_in[1];
    const float* qkv_wb = (const float*)d_in[2];
    const float* qkv_ws = (const float*)d_in[3];
    const float* lng    = (const float*)d_in[4];
    const float* lnb    = (const float*)d_in[5];
    const float* gt_wb  = (const float*)d_in[6];
    const float* gt_ws  = (const float*)d_in[7];
    const float* out_wb = (const float*)d_in[8];
    const float* out_ws = (const float*)d_in[9];
    float* out = (float*)d_out;
    float* ws  = (float*)d_ws;

    const size_t OFF_QKV   = 0;            // 40,108,032 floats (window-major)
    const size_t OFF_FMAP  = 0;            // reuses dead qkv region
    const size_t OFF_WF2   = 40108032;     // 165,888 floats
    const size_t OFF_GT    = OFF_WF2 + 165888;   // (unused; kept for layout)
    const size_t OFF_GF    = OFF_GT + 786432;
    const size_t OFF_HH    = OFF_GF + 12582912;
    const size_t OFF_QK    = OFF_HH + 786432;   // col-major [8192][192]
    const size_t OFF_WF1   = OFF_QK + 1572864;  // 248,832 floats
    const size_t OFF_WF3   = OFF_WF1 + 248832;  // 82,944 floats
    const size_t TOTAL     = OFF_WF3 + 82944;   // 56,334,336 floats
    if (ws_size < TOTAL * sizeof(float)) return;

    unsigned short* wf1 = (unsigned short*)(ws + OFF_WF1);
    unsigned short* wf2 = (unsigned short*)(ws + OFF_WF2);
    unsigned short* wf3 = (unsigned short*)(ws + OFF_WF3);

    prep_all<<<486, 256, 0, stream>>>(qkv_wb, qkv_ws, wf1,
                                      gt_wb,  gt_ws,  wf2,
                                      out_wb, out_ws, wf3);

    kan_mfma<9, 0><<<1632, 256, 0, stream>>>(x, tok, wf1, ws + OFF_QKV);
    attn1<<<8192, 256, 0, stream>>>(ws + OFF_QKV, lng, lnb, ws + OFF_GF, ws + OFF_HH);
    kan_mfma<6, 2><<<64, 256, 0, stream>>>(ws + OFF_HH, nullptr, wf2, ws + OFF_QK);
    attn2<<<384, 256, 0, stream>>>(ws + OFF_QK, ws + OFF_GF, ws + OFF_FMAP);
    kan_mfma_fmap<<<1024, 256, 0, stream>>>(ws + OFF_FMAP, wf3, out);
}